// Round 1
// baseline (1872.631 us; speedup 1.0000x reference)
//
#include <hip/hip_runtime.h>
#include <hip/hip_bf16.h>

// QuantizedMoEExpert: out[8192,14336] = x[8192,4096] @ dequant(packed)[14336,4096]^T
// Round 2: split into (a) X fp32->bf16 pre-pass, (b) weight dequant pre-pass,
// (c) pure bf16 MFMA GEMM (m97 structure: 128x128 tile, BK=64, global_load_lds
// width-16 staging, XCD-swizzled blockIdx). Removes the 64x-redundant in-loop
// dequant VALU work that capped the fused kernel at MfmaUtil~31 / VALUBusy~57.
// Falls back to the round-1 fused kernel if the workspace is too small.

typedef __bf16 bf16x8 __attribute__((ext_vector_type(8)));
typedef __bf16 bf16x4 __attribute__((ext_vector_type(4)));
typedef float floatx4 __attribute__((ext_vector_type(4)));

#define M_DIM 8192
#define K_DIM 4096
#define N_DIM 14336
#define KB    (K_DIM / 2)   // packed int32 elements per output row (2 nibbles each)

#define BM 128
#define BN 128
#define BK 64
#define LDSK 72             // fallback kernel only

// ---------------------------------------------------------------------------
// async global->LDS copy, 16B per lane (wave-uniform LDS base + lane*16)
// ---------------------------------------------------------------------------
__device__ __forceinline__ void async_ld16(const __bf16* g, __bf16* l) {
    __builtin_amdgcn_global_load_lds(
        (const __attribute__((address_space(1))) void*)g,
        (__attribute__((address_space(3))) void*)l,
        16, 0, 0);
}

// ---------------------------------------------------------------------------
// Pre-pass 1: X fp32 [M,K] -> bf16 [M,K]
// ---------------------------------------------------------------------------
__global__ __launch_bounds__(256) void cvt_x_kernel(
    const float* __restrict__ X, __bf16* __restrict__ XB)
{
    const size_t n8 = (size_t)M_DIM * K_DIM / 8;
    const size_t stride = (size_t)gridDim.x * blockDim.x;
    for (size_t i = (size_t)blockIdx.x * blockDim.x + threadIdx.x; i < n8; i += stride) {
        float4 a = ((const float4*)X)[2 * i];
        float4 b = ((const float4*)X)[2 * i + 1];
        bf16x8 w;
        w[0] = (__bf16)a.x; w[1] = (__bf16)a.y; w[2] = (__bf16)a.z; w[3] = (__bf16)a.w;
        w[4] = (__bf16)b.x; w[5] = (__bf16)b.y; w[6] = (__bf16)b.z; w[7] = (__bf16)b.w;
        ((bf16x8*)XB)[i] = w;
    }
}

// ---------------------------------------------------------------------------
// Pre-pass 2: dequant packed int4 pairs -> W bf16 [N,K] row-major
// Each int32 holds one byte: low nibble = even col, high nibble = odd col.
// ---------------------------------------------------------------------------
__global__ __launch_bounds__(256) void dequant_w_kernel(
    const int* __restrict__ P, const float* __restrict__ S,
    const float* __restrict__ Z, __bf16* __restrict__ WB)
{
    const size_t n4 = (size_t)N_DIM * KB / 4;       // int4 chunks (4 int32 -> 8 bf16)
    const size_t stride = (size_t)gridDim.x * blockDim.x;
    for (size_t i = (size_t)blockIdx.x * blockDim.x + threadIdx.x; i < n4; i += stride) {
        const int row = (int)(i >> 9);              // KB/4 = 512 chunks per row
        const float s = S[row];
        const float o = -Z[row] * s;                // w = v*s + (-z*s)
        int4 b = ((const int4*)P)[i];
        bf16x8 w;
        w[0] = (__bf16)((float)(b.x & 15) * s + o);
        w[1] = (__bf16)((float)((b.x >> 4) & 15) * s + o);
        w[2] = (__bf16)((float)(b.y & 15) * s + o);
        w[3] = (__bf16)((float)((b.y >> 4) & 15) * s + o);
        w[4] = (__bf16)((float)(b.z & 15) * s + o);
        w[5] = (__bf16)((float)((b.z >> 4) & 15) * s + o);
        w[6] = (__bf16)((float)(b.w & 15) * s + o);
        w[7] = (__bf16)((float)((b.w >> 4) & 15) * s + o);
        ((bf16x8*)WB)[i] = w;
    }
}

// ---------------------------------------------------------------------------
// Main GEMM: O[M,N] = A[M,K](bf16) @ B[N,K](bf16)^T, fp32 out.
// m97 structure: 128x128 tile, BK=64, 4 waves (2x2 of 64x64), 16x16x32 MFMA,
// linear LDS + global_load_lds dwordx4 staging, 2 barriers per K-step.
// ---------------------------------------------------------------------------
__global__ __launch_bounds__(256) void gemm_bf16_2p(
    const __bf16* __restrict__ A,   // [M, K]
    const __bf16* __restrict__ B,   // [N, K]
    float*        __restrict__ O)   // [M, N]
{
    __shared__ __bf16 Alds[BM * BK];
    __shared__ __bf16 Blds[BN * BK];

    const int t    = threadIdx.x;
    const int lane = t & 63;
    const int wave = t >> 6;

    // XCD-aware swizzle: nwg = 7168, nwg % 8 == 0 -> simple form is bijective.
    const int nwg  = (N_DIM / BN) * (M_DIM / BM);
    const int orig = blockIdx.x;
    const int swz  = (orig & 7) * (nwg >> 3) + (orig >> 3);
    const int bn   = swz % (N_DIM / BN);
    const int bm   = swz / (N_DIM / BN);

    // staging map: wave owns 32 rows of each tile; one issue = 8 rows = 1024B.
    // lane l covers row (l>>3), 16B block (l&7) -> LDS offset l*16 (linear).
    const int srow = lane >> 3;
    const int scol = (lane & 7) * 8;
    const __bf16* aG = A + (size_t)(bm * BM + wave * 32 + srow) * K_DIM + scol;
    const __bf16* bG = B + (size_t)(bn * BN + wave * 32 + srow) * K_DIM + scol;
    __bf16* aL = &Alds[(wave * 32) * BK];
    __bf16* bL = &Blds[(wave * 32) * BK];

    // compute map: 2x2 waves of 64x64; 4x4 fragments of 16x16 each.
    const int wm   = wave >> 1;
    const int wn   = wave & 1;
    const int fr   = lane & 15;
    const int quad = lane >> 4;

    floatx4 acc[4][4];
    for (int i = 0; i < 4; ++i)
        for (int j = 0; j < 4; ++j)
            acc[i][j] = (floatx4)0.0f;

    const __bf16* aF = &Alds[(wm * 64 + fr) * BK + quad * 8];
    const __bf16* bF = &Blds[(wn * 64 + fr) * BK + quad * 8];

    for (int kt = 0; kt < K_DIM / BK; ++kt) {
#pragma unroll
        for (int i = 0; i < 4; ++i) {
            async_ld16(aG + (size_t)(i * 8) * K_DIM, aL + i * 8 * BK);
            async_ld16(bG + (size_t)(i * 8) * K_DIM, bL + i * 8 * BK);
        }
        aG += BK;
        bG += BK;
        __syncthreads();   // compiler drains vmcnt(0) here -> LDS tiles valid

#pragma unroll
        for (int kk = 0; kk < BK; kk += 32) {
            bf16x8 af[4], bv[4];
            for (int i = 0; i < 4; ++i)
                af[i] = *(const bf16x8*)(aF + i * 16 * BK + kk);
            for (int j = 0; j < 4; ++j)
                bv[j] = *(const bf16x8*)(bF + j * 16 * BK + kk);
            for (int i = 0; i < 4; ++i)
                for (int j = 0; j < 4; ++j)
                    acc[i][j] = __builtin_amdgcn_mfma_f32_16x16x32_bf16(
                        af[i], bv[j], acc[i][j], 0, 0, 0);
        }
        __syncthreads();
    }

    // epilogue: C/D layout col=lane&15, row=quad*4+reg
    for (int i = 0; i < 4; ++i) {
        const int row = bm * BM + wm * 64 + i * 16 + quad * 4;
        for (int j = 0; j < 4; ++j) {
            const int col = bn * BN + wn * 64 + j * 16 + fr;
            float* o = O + (size_t)row * N_DIM + col;
            for (int r = 0; r < 4; ++r)
                o[(size_t)r * N_DIM] = acc[i][j][r];
        }
    }
}

// ---------------------------------------------------------------------------
// Round-1 fused kernel (fallback if workspace is too small).
// ---------------------------------------------------------------------------
__global__ __launch_bounds__(256) void qgemm_bf16(
    const float* __restrict__ X,   // [M, K] fp32
    const int*   __restrict__ P,   // [N, K/2] packed int4 pairs
    const float* __restrict__ S,   // [N] scales
    const float* __restrict__ Z,   // [N] zero points
    float*       __restrict__ O)   // [M, N]
{
    __shared__ __bf16 Alds[BM * LDSK];
    __shared__ __bf16 Blds[BN * LDSK];

    const int t  = threadIdx.x;
    const int bn = blockIdx.x;
    const int bm = blockIdx.y;

    const int rowA0 = t >> 4;
    const int c4    = t & 15;
    const int rowB0 = t >> 3;
    const int cB    = t & 7;

    const float* aG = X + (size_t)(bm * BM + rowA0) * K_DIM + c4 * 4;
    const int*   bG = P + (size_t)(bn * BN + rowB0) * KB    + cB * 4;

    float sreg[4], oreg[4];
    for (int it = 0; it < 4; ++it) {
        int r = bn * BN + rowB0 + 32 * it;
        float s = S[r], z = Z[r];
        sreg[it] = s;
        oreg[it] = -z * s;
    }

    const int lane = t & 63;
    const int wave = t >> 6;
    const int wm   = wave >> 1;
    const int wn   = wave & 1;
    const int fr   = lane & 15;
    const int quad = lane >> 4;

    floatx4 acc[4][4];
    for (int i = 0; i < 4; ++i)
        for (int j = 0; j < 4; ++j)
            acc[i][j] = (floatx4)0.0f;

    const __bf16* aBase = &Alds[(wm * 64 + fr) * LDSK + quad * 8];
    const __bf16* bBase = &Blds[(wn * 64 + fr) * LDSK + quad * 8];

    for (int kt = 0; kt < K_DIM / BK; ++kt) {
        float4 av[8];
        for (int it = 0; it < 8; ++it)
            av[it] = *(const float4*)(aG + (size_t)it * 16 * K_DIM);
        int4 bv[4];
        for (int it = 0; it < 4; ++it)
            bv[it] = *(const int4*)(bG + (size_t)it * 32 * KB);
        aG += BK;
        bG += BK / 2;

        for (int it = 0; it < 8; ++it) {
            bf16x4 w;
            w[0] = (__bf16)av[it].x;
            w[1] = (__bf16)av[it].y;
            w[2] = (__bf16)av[it].z;
            w[3] = (__bf16)av[it].w;
            *(bf16x4*)&Alds[(rowA0 + 16 * it) * LDSK + c4 * 4] = w;
        }
        for (int it = 0; it < 4; ++it) {
            const float s = sreg[it], o = oreg[it];
            const int b0 = bv[it].x, b1 = bv[it].y, b2 = bv[it].z, b3 = bv[it].w;
            bf16x8 w;
            w[0] = (__bf16)((float)(b0 & 15) * s + o);
            w[1] = (__bf16)((float)((b0 >> 4) & 15) * s + o);
            w[2] = (__bf16)((float)(b1 & 15) * s + o);
            w[3] = (__bf16)((float)((b1 >> 4) & 15) * s + o);
            w[4] = (__bf16)((float)(b2 & 15) * s + o);
            w[5] = (__bf16)((float)((b2 >> 4) & 15) * s + o);
            w[6] = (__bf16)((float)(b3 & 15) * s + o);
            w[7] = (__bf16)((float)((b3 >> 4) & 15) * s + o);
            *(bf16x8*)&Blds[(rowB0 + 32 * it) * LDSK + cB * 8] = w;
        }
        __syncthreads();

        for (int kk = 0; kk < BK; kk += 32) {
            bf16x8 af[4], bf[4];
            for (int i = 0; i < 4; ++i)
                af[i] = *(const bf16x8*)(aBase + (i * 16) * LDSK + kk);
            for (int j = 0; j < 4; ++j)
                bf[j] = *(const bf16x8*)(bBase + (j * 16) * LDSK + kk);
            for (int i = 0; i < 4; ++i)
                for (int j = 0; j < 4; ++j)
                    acc[i][j] = __builtin_amdgcn_mfma_f32_16x16x32_bf16(
                        af[i], bf[j], acc[i][j], 0, 0, 0);
        }
        __syncthreads();
    }

    for (int i = 0; i < 4; ++i) {
        const int row = bm * BM + wm * 64 + i * 16 + quad * 4;
        for (int j = 0; j < 4; ++j) {
            const int col = bn * BN + wn * 64 + j * 16 + fr;
            float* o = O + (size_t)row * N_DIM + col;
            for (int r = 0; r < 4; ++r)
                o[(size_t)r * N_DIM] = acc[i][j][r];
        }
    }
}

// ---------------------------------------------------------------------------
extern "C" void kernel_launch(void* const* d_in, const int* in_sizes, int n_in,
                              void* d_out, int out_size, void* d_ws, size_t ws_size,
                              hipStream_t stream) {
    const float* x = (const float*)d_in[0];
    const int*   p = (const int*)d_in[1];
    const float* s = (const float*)d_in[2];
    const float* z = (const float*)d_in[3];
    float* out = (float*)d_out;

    const size_t bytesX = (size_t)M_DIM * K_DIM * 2;   // 67.1 MB
    const size_t bytesW = (size_t)N_DIM * K_DIM * 2;   // 117.4 MB

    if (d_ws != nullptr && ws_size >= bytesX + bytesW) {
        __bf16* xb = (__bf16*)d_ws;
        __bf16* wb = (__bf16*)((char*)d_ws + bytesX);
        cvt_x_kernel<<<2048, 256, 0, stream>>>(x, xb);
        dequant_w_kernel<<<2048, 256, 0, stream>>>(p, s, z, wb);
        const int nwg = (N_DIM / BN) * (M_DIM / BM);   // 112*64 = 7168
        gemm_bf16_2p<<<nwg, 256, 0, stream>>>(xb, wb, out);
    } else {
        dim3 grid(N_DIM / BN, M_DIM / BM);
        qgemm_bf16<<<grid, 256, 0, stream>>>(x, p, s, z, out);
    }
}

// Round 2
// 1676.514 us; speedup vs baseline: 1.1170x; 1.1170x over previous
//
#include <hip/hip_runtime.h>
#include <hip/hip_bf16.h>

// QuantizedMoEExpert: out[8192,14336] = x[8192,4096] @ dequant(packed)[14336,4096]^T
// Round 3: fix the 32-way LDS bank conflict in the bf16 GEMM.
//   Round-2 counters: SQ_LDS_BANK_CONFLICT 3.5e8 (20x the m97 reference),
//   MfmaUtil 30%, VALUBusy 21% -> ds_read serialization is the binding pipe.
//   Linear [128][64] bf16 LDS = 128B row stride = all 16 lanes of a quad in
//   one bank slot. Fix per rule #21: keep LDS writes linear (global_load_lds
//   constraint), pre-swizzle the per-lane GLOBAL source column by
//   blk ^= (row&7), and apply the same XOR on the ds_read side.
// Pre-passes (X fp32->bf16, W dequant->bf16) unchanged from round 2.

typedef __bf16 bf16x8 __attribute__((ext_vector_type(8)));
typedef __bf16 bf16x4 __attribute__((ext_vector_type(4)));
typedef float floatx4 __attribute__((ext_vector_type(4)));

#define M_DIM 8192
#define K_DIM 4096
#define N_DIM 14336
#define KB    (K_DIM / 2)   // packed int32 elements per output row (2 nibbles each)

#define BM 128
#define BN 128
#define BK 64
#define LDSK 72             // fallback kernel only

// ---------------------------------------------------------------------------
// async global->LDS copy, 16B per lane (wave-uniform LDS base + lane*16)
// ---------------------------------------------------------------------------
__device__ __forceinline__ void async_ld16(const __bf16* g, __bf16* l) {
    __builtin_amdgcn_global_load_lds(
        (const __attribute__((address_space(1))) void*)g,
        (__attribute__((address_space(3))) void*)l,
        16, 0, 0);
}

// ---------------------------------------------------------------------------
// Pre-pass 1: X fp32 [M,K] -> bf16 [M,K]
// ---------------------------------------------------------------------------
__global__ __launch_bounds__(256) void cvt_x_kernel(
    const float* __restrict__ X, __bf16* __restrict__ XB)
{
    const size_t n8 = (size_t)M_DIM * K_DIM / 8;
    const size_t stride = (size_t)gridDim.x * blockDim.x;
    for (size_t i = (size_t)blockIdx.x * blockDim.x + threadIdx.x; i < n8; i += stride) {
        float4 a = ((const float4*)X)[2 * i];
        float4 b = ((const float4*)X)[2 * i + 1];
        bf16x8 w;
        w[0] = (__bf16)a.x; w[1] = (__bf16)a.y; w[2] = (__bf16)a.z; w[3] = (__bf16)a.w;
        w[4] = (__bf16)b.x; w[5] = (__bf16)b.y; w[6] = (__bf16)b.z; w[7] = (__bf16)b.w;
        ((bf16x8*)XB)[i] = w;
    }
}

// ---------------------------------------------------------------------------
// Pre-pass 2: dequant packed int4 pairs -> W bf16 [N,K] row-major
// ---------------------------------------------------------------------------
__global__ __launch_bounds__(256) void dequant_w_kernel(
    const int* __restrict__ P, const float* __restrict__ S,
    const float* __restrict__ Z, __bf16* __restrict__ WB)
{
    const size_t n4 = (size_t)N_DIM * KB / 4;       // int4 chunks (4 int32 -> 8 bf16)
    const size_t stride = (size_t)gridDim.x * blockDim.x;
    for (size_t i = (size_t)blockIdx.x * blockDim.x + threadIdx.x; i < n4; i += stride) {
        const int row = (int)(i >> 9);              // KB/4 = 512 chunks per row
        const float s = S[row];
        const float o = -Z[row] * s;                // w = v*s + (-z*s)
        int4 b = ((const int4*)P)[i];
        bf16x8 w;
        w[0] = (__bf16)((float)(b.x & 15) * s + o);
        w[1] = (__bf16)((float)((b.x >> 4) & 15) * s + o);
        w[2] = (__bf16)((float)(b.y & 15) * s + o);
        w[3] = (__bf16)((float)((b.y >> 4) & 15) * s + o);
        w[4] = (__bf16)((float)(b.z & 15) * s + o);
        w[5] = (__bf16)((float)((b.z >> 4) & 15) * s + o);
        w[6] = (__bf16)((float)(b.w & 15) * s + o);
        w[7] = (__bf16)((float)((b.w >> 4) & 15) * s + o);
        ((bf16x8*)WB)[i] = w;
    }
}

// ---------------------------------------------------------------------------
// Main GEMM: O[M,N] = A[M,K](bf16) @ B[N,K](bf16)^T, fp32 out.
// m97 structure + XOR block-swizzle:
//   LDS tile [128][64] bf16, rows of 8 x 16B blocks.
//   LDS (row, blk) holds global (row, blk ^ (row&7)).
//   Write side: linear global_load_lds; lane l's global col = ((l&7)^(l>>3))*8.
//   Read side:  fragment block = (quad + kk/8) ^ (fr&7).
// ---------------------------------------------------------------------------
__global__ __launch_bounds__(256) void gemm_bf16_2p(
    const __bf16* __restrict__ A,   // [M, K]
    const __bf16* __restrict__ B,   // [N, K]
    float*        __restrict__ O)   // [M, N]
{
    __shared__ __bf16 Alds[BM * BK];
    __shared__ __bf16 Blds[BN * BK];

    const int t    = threadIdx.x;
    const int lane = t & 63;
    const int wave = t >> 6;

    // XCD-aware swizzle: nwg = 7168, nwg % 8 == 0 -> simple form is bijective.
    const int nwg  = (N_DIM / BN) * (M_DIM / BM);
    const int orig = blockIdx.x;
    const int swz  = (orig & 7) * (nwg >> 3) + (orig >> 3);
    const int bn   = swz % (N_DIM / BN);
    const int bm   = swz / (N_DIM / BN);

    // staging map: wave owns 32 rows; one issue = 8 rows = 1024B linear LDS.
    // lane l -> LDS (row l>>3, blk l&7); global source blk = (l&7)^(l>>3).
    const int srow = lane >> 3;
    const int sblk = (lane & 7) ^ srow;
    const __bf16* aG = A + (size_t)(bm * BM + wave * 32 + srow) * K_DIM + sblk * 8;
    const __bf16* bG = B + (size_t)(bn * BN + wave * 32 + srow) * K_DIM + sblk * 8;
    __bf16* aL = &Alds[(wave * 32) * BK];
    __bf16* bL = &Blds[(wave * 32) * BK];

    // compute map: 2x2 waves of 64x64; 4x4 fragments of 16x16 each.
    const int wm   = wave >> 1;
    const int wn   = wave & 1;
    const int fr   = lane & 15;
    const int quad = lane >> 4;
    const int xr   = fr & 7;        // tile-row low bits for read-side unswizzle

    floatx4 acc[4][4];
    for (int i = 0; i < 4; ++i)
        for (int j = 0; j < 4; ++j)
            acc[i][j] = (floatx4)0.0f;

    const int rowA = wm * 64 + fr;  // + i*16 per fragment (i*16 mult of 8 -> row&7 = xr)
    const int rowB = wn * 64 + fr;

    for (int kt = 0; kt < K_DIM / BK; ++kt) {
#pragma unroll
        for (int i = 0; i < 4; ++i) {
            async_ld16(aG + (size_t)(i * 8) * K_DIM, aL + i * 8 * BK);
            async_ld16(bG + (size_t)(i * 8) * K_DIM, bL + i * 8 * BK);
        }
        aG += BK;
        bG += BK;
        __syncthreads();   // compiler drains vmcnt(0) here -> LDS tiles valid

#pragma unroll
        for (int kk8 = 0; kk8 < 2; ++kk8) {          // kk = kk8*32 elems = kk8*4 blocks
            const int blk = (quad + kk8 * 4) ^ xr;   // swizzled 16B block within row
            bf16x8 af[4], bv[4];
            for (int i = 0; i < 4; ++i)
                af[i] = *(const bf16x8*)(&Alds[(rowA + i * 16) * BK + blk * 8]);
            for (int j = 0; j < 4; ++j)
                bv[j] = *(const bf16x8*)(&Blds[(rowB + j * 16) * BK + blk * 8]);
            for (int i = 0; i < 4; ++i)
                for (int j = 0; j < 4; ++j)
                    acc[i][j] = __builtin_amdgcn_mfma_f32_16x16x32_bf16(
                        af[i], bv[j], acc[i][j], 0, 0, 0);
        }
        __syncthreads();
    }

    // epilogue: C/D layout col=lane&15, row=quad*4+reg
    for (int i = 0; i < 4; ++i) {
        const int row = bm * BM + wm * 64 + i * 16 + quad * 4;
        for (int j = 0; j < 4; ++j) {
            const int col = bn * BN + wn * 64 + j * 16 + fr;
            float* o = O + (size_t)row * N_DIM + col;
            for (int r = 0; r < 4; ++r)
                o[(size_t)r * N_DIM] = acc[i][j][r];
        }
    }
}

// ---------------------------------------------------------------------------
// Round-1 fused kernel (fallback if workspace is too small).
// ---------------------------------------------------------------------------
__global__ __launch_bounds__(256) void qgemm_bf16(
    const float* __restrict__ X,   // [M, K] fp32
    const int*   __restrict__ P,   // [N, K/2] packed int4 pairs
    const float* __restrict__ S,   // [N] scales
    const float* __restrict__ Z,   // [N] zero points
    float*       __restrict__ O)   // [M, N]
{
    __shared__ __bf16 Alds[BM * LDSK];
    __shared__ __bf16 Blds[BN * LDSK];

    const int t  = threadIdx.x;
    const int bn = blockIdx.x;
    const int bm = blockIdx.y;

    const int rowA0 = t >> 4;
    const int c4    = t & 15;
    const int rowB0 = t >> 3;
    const int cB    = t & 7;

    const float* aG = X + (size_t)(bm * BM + rowA0) * K_DIM + c4 * 4;
    const int*   bG = P + (size_t)(bn * BN + rowB0) * KB    + cB * 4;

    float sreg[4], oreg[4];
    for (int it = 0; it < 4; ++it) {
        int r = bn * BN + rowB0 + 32 * it;
        float s = S[r], z = Z[r];
        sreg[it] = s;
        oreg[it] = -z * s;
    }

    const int lane = t & 63;
    const int wave = t >> 6;
    const int wm   = wave >> 1;
    const int wn   = wave & 1;
    const int fr   = lane & 15;
    const int quad = lane >> 4;

    floatx4 acc[4][4];
    for (int i = 0; i < 4; ++i)
        for (int j = 0; j < 4; ++j)
            acc[i][j] = (floatx4)0.0f;

    const __bf16* aBase = &Alds[(wm * 64 + fr) * LDSK + quad * 8];
    const __bf16* bBase = &Blds[(wn * 64 + fr) * LDSK + quad * 8];

    for (int kt = 0; kt < K_DIM / BK; ++kt) {
        float4 av[8];
        for (int it = 0; it < 8; ++it)
            av[it] = *(const float4*)(aG + (size_t)it * 16 * K_DIM);
        int4 bv[4];
        for (int it = 0; it < 4; ++it)
            bv[it] = *(const int4*)(bG + (size_t)it * 32 * KB);
        aG += BK;
        bG += BK / 2;

        for (int it = 0; it < 8; ++it) {
            bf16x4 w;
            w[0] = (__bf16)av[it].x;
            w[1] = (__bf16)av[it].y;
            w[2] = (__bf16)av[it].z;
            w[3] = (__bf16)av[it].w;
            *(bf16x4*)&Alds[(rowA0 + 16 * it) * LDSK + c4 * 4] = w;
        }
        for (int it = 0; it < 4; ++it) {
            const float s = sreg[it], o = oreg[it];
            const int b0 = bv[it].x, b1 = bv[it].y, b2 = bv[it].z, b3 = bv[it].w;
            bf16x8 w;
            w[0] = (__bf16)((float)(b0 & 15) * s + o);
            w[1] = (__bf16)((float)((b0 >> 4) & 15) * s + o);
            w[2] = (__bf16)((float)(b1 & 15) * s + o);
            w[3] = (__bf16)((float)((b1 >> 4) & 15) * s + o);
            w[4] = (__bf16)((float)(b2 & 15) * s + o);
            w[5] = (__bf16)((float)((b2 >> 4) & 15) * s + o);
            w[6] = (__bf16)((float)(b3 & 15) * s + o);
            w[7] = (__bf16)((float)((b3 >> 4) & 15) * s + o);
            *(bf16x8*)&Blds[(rowB0 + 32 * it) * LDSK + cB * 8] = w;
        }
        __syncthreads();

        for (int kk = 0; kk < BK; kk += 32) {
            bf16x8 af[4], bf[4];
            for (int i = 0; i < 4; ++i)
                af[i] = *(const bf16x8*)(aBase + (i * 16) * LDSK + kk);
            for (int j = 0; j < 4; ++j)
                bf[j] = *(const bf16x8*)(bBase + (j * 16) * LDSK + kk);
            for (int i = 0; i < 4; ++i)
                for (int j = 0; j < 4; ++j)
                    acc[i][j] = __builtin_amdgcn_mfma_f32_16x16x32_bf16(
                        af[i], bf[j], acc[i][j], 0, 0, 0);
        }
        __syncthreads();
    }

    for (int i = 0; i < 4; ++i) {
        const int row = bm * BM + wm * 64 + i * 16 + quad * 4;
        for (int j = 0; j < 4; ++j) {
            const int col = bn * BN + wn * 64 + j * 16 + fr;
            float* o = O + (size_t)row * N_DIM + col;
            for (int r = 0; r < 4; ++r)
                o[(size_t)r * N_DIM] = acc[i][j][r];
        }
    }
}

// ---------------------------------------------------------------------------
extern "C" void kernel_launch(void* const* d_in, const int* in_sizes, int n_in,
                              void* d_out, int out_size, void* d_ws, size_t ws_size,
                              hipStream_t stream) {
    const float* x = (const float*)d_in[0];
    const int*   p = (const int*)d_in[1];
    const float* s = (const float*)d_in[2];
    const float* z = (const float*)d_in[3];
    float* out = (float*)d_out;

    const size_t bytesX = (size_t)M_DIM * K_DIM * 2;   // 67.1 MB
    const size_t bytesW = (size_t)N_DIM * K_DIM * 2;   // 117.4 MB

    if (d_ws != nullptr && ws_size >= bytesX + bytesW) {
        __bf16* xb = (__bf16*)d_ws;
        __bf16* wb = (__bf16*)((char*)d_ws + bytesX);
        cvt_x_kernel<<<2048, 256, 0, stream>>>(x, xb);
        dequant_w_kernel<<<2048, 256, 0, stream>>>(p, s, z, wb);
        const int nwg = (N_DIM / BN) * (M_DIM / BM);   // 112*64 = 7168
        gemm_bf16_2p<<<nwg, 256, 0, stream>>>(xb, wb, out);
    } else {
        dim3 grid(N_DIM / BN, M_DIM / BM);
        qgemm_bf16<<<grid, 256, 0, stream>>>(x, p, s, z, out);
    }
}